// Round 1
// baseline (1066.695 us; speedup 1.0000x reference)
//
#include <hip/hip_runtime.h>
#include <stdint.h>
#include <math.h>

// ---------------------------------------------------------------- constants
#define DIM     1024
#define HID     4096
#define SEQ     2048
#define NB      4
#define NH      16
#define HD      64
#define NCHUNK  32          // SEQ / 64
#define MROWS   8192        // NB * SEQ
#define QSTR    3072        // fused qkv row stride

typedef unsigned short ushort_t;
typedef __attribute__((ext_vector_type(8))) short bf16x8;
typedef __attribute__((ext_vector_type(4))) float f32x4;

// ws layout (bytes) — peak ~193.5 MB, proven non-faulting
#define OFF_H    ((size_t)0)            // bf16 [8192][1024]
#define OFF_Q    ((size_t)16777216)     // bf16 [8192][3072] fused qkv
#define OFF_P    ((size_t)67108864)     // f32 [64][32][4096]
#define OFF_KS   ((size_t)100663296)    // f32 [64][32][64]
#define OFF_X1   ((size_t)101187584)    // f32 [8192][1024]
#define OFF_WQT  ((size_t)134742016)    // bf16 [3072][1024] fused qkv weights^T
#define OFF_WOT  ((size_t)141033472)
#define OFF_W1T  ((size_t)143130624)    // 3 x bf16 [4096][1024]
#define OFF_W2T  ((size_t)168296448)    // 3 x bf16 [1024][4096]
#define OFF_HIDB OFF_Q + 16777216       // bf16 [8192][4096]: spans old K,V,P (dead at CMS time)

__device__ __forceinline__ float b2f(ushort_t u) {
    return __uint_as_float(((unsigned int)u) << 16);
}
__device__ __forceinline__ ushort_t f2b(float f) {
    unsigned int u = __float_as_uint(f);
    u += 0x7FFFu + ((u >> 16) & 1u);          // round-to-nearest-even
    return (ushort_t)(u >> 16);
}
__device__ __forceinline__ void unpack4(uint2 u, float* f) {
    f[0] = __uint_as_float(u.x << 16);
    f[1] = __uint_as_float(u.x & 0xffff0000u);
    f[2] = __uint_as_float(u.y << 16);
    f[3] = __uint_as_float(u.y & 0xffff0000u);
}
// gelu(tanh form) == x*sigmoid(2z); ~7 VALU ops vs ~40 for libm tanhf
__device__ __forceinline__ float fast_gelu(float x) {
    const float u = x * (1.5957691216057308f + 0.07135481627f * x * x);  // 2z
    const float e = exp2f(-1.4426950408889634f * u);
    return x * __builtin_amdgcn_rcpf(1.0f + e);
}
__device__ __forceinline__ float fast_elu1(float x) {
    return x > 0.0f ? x + 1.0f : exp2f(1.4426950408889634f * x);
}
// async 16B global->LDS DMA; LDS dest must be wave-uniform base + lane*16 [m97/m104]
__device__ __forceinline__ void ldg16(const ushort_t* g, ushort_t* l) {
    __builtin_amdgcn_global_load_lds(
        (const __attribute__((address_space(1))) void*)g,
        (__attribute__((address_space(3))) void*)l, 16, 0, 0);
}

// ---------------------------------------------------------------- transpose (f32 -> bf16)
__global__ void __launch_bounds__(256)
transpose_f32_bf16(const float* __restrict__ src, ushort_t* __restrict__ dst, int R, int C)
{
    __shared__ float t[32][33];
    const int bx = blockIdx.x * 32;
    const int by = blockIdx.y * 32;
    const int tx = threadIdx.x, ty = threadIdx.y;
    #pragma unroll
    for (int i = ty; i < 32; i += 8)
        t[i][tx] = src[(size_t)(by + i) * C + bx + tx];
    __syncthreads();
    #pragma unroll
    for (int i = ty; i < 32; i += 8)
        dst[(size_t)(bx + i) * R + by + tx] = f2b(t[tx][i]);
}

// ---------------------------------------------------------------- layernorm (f32 in, bf16 out)
__global__ void __launch_bounds__(256)
ln_fwd(const float* __restrict__ xin, const float* __restrict__ g,
       const float* __restrict__ be, ushort_t* __restrict__ out)
{
    const int row = blockIdx.x, tid = threadIdx.x;
    const float4 f = ((const float4*)(xin + (size_t)row * DIM))[tid];
    float v[4] = {f.x, f.y, f.z, f.w};
    float s  = v[0] + v[1] + v[2] + v[3];
    float ss = v[0]*v[0] + v[1]*v[1] + v[2]*v[2] + v[3]*v[3];
    #pragma unroll
    for (int off = 32; off; off >>= 1) {
        s  += __shfl_down(s, off);
        ss += __shfl_down(ss, off);
    }
    __shared__ float red[2][4];
    const int wave = tid >> 6, lane = tid & 63;
    if (lane == 0) { red[0][wave] = s; red[1][wave] = ss; }
    __syncthreads();
    s  = red[0][0] + red[0][1] + red[0][2] + red[0][3];
    ss = red[1][0] + red[1][1] + red[1][2] + red[1][3];
    const float mean = s * (1.0f / DIM);
    const float var  = ss * (1.0f / DIM) - mean * mean;
    const float rstd = rsqrtf(var + 1e-5f);
    ushort_t o[4];
    #pragma unroll
    for (int i = 0; i < 4; i++) {
        const int col = tid * 4 + i;
        o[i] = f2b((v[i] - mean) * rstd * g[col] + be[col]);
    }
    uint2 u2;
    u2.x = (unsigned int)o[0] | ((unsigned int)o[1] << 16);
    u2.y = (unsigned int)o[2] | ((unsigned int)o[3] << 16);
    *(uint2*)(out + (size_t)row * DIM + tid * 4) = u2;
}

#define ACT_NONE 0
#define ACT_ELU1 1
#define ACT_GELU 2
#define ACT_QKV  3   // cols < 2048 -> elu+1 (Q,K); cols >= 2048 -> none (V). block-uniform.

// ---------------------------------------------------------------- GEMM (old 128x128, kept as fallback; unused)
template<int ACT, bool BIAS, bool RES, bool OUTF32>
__global__ void __launch_bounds__(256, 4)
gemm_bt(const ushort_t* __restrict__ A, const ushort_t* __restrict__ Bt,
        const float* __restrict__ bias, const float* __restrict__ resid,
        void* __restrict__ Cout, int M, int N, int K)
{
    __shared__ __align__(16) ushort_t As[2][128 * 32];
    __shared__ __align__(16) ushort_t Bs[2][128 * 32];
    const int tid  = threadIdx.x;
    const int wave = tid >> 6, lane = tid & 63;
    const int bm = blockIdx.x * 128, bn = blockIdx.y * 128;
    const int wm = (wave >> 1) * 64, wn = (wave & 1) * 64;
    const int skp  = (tid & 3) * 8;
    const int srow = tid >> 2;
    const int mrow = lane & 15, kq = (lane >> 4) * 8;
    const bool qkv_elu = (bn < 2048);

    f32x4 acc[4][4] = {};
    const size_t arow0 = (size_t)(bm + srow)      * K;
    const size_t arow1 = (size_t)(bm + srow + 64) * K;
    const size_t brow0 = (size_t)(bn + srow)      * K;
    const size_t brow1 = (size_t)(bn + srow + 64) * K;

    for (int kt = 0; kt < K; kt += 64) {
        __syncthreads();
        #pragma unroll
        for (int hh = 0; hh < 2; hh++) {
            const int ko = kt + hh * 32;
            ldg16(A  + arow0 + ko + skp, As[hh] + tid * 8);
            ldg16(A  + arow1 + ko + skp, As[hh] + 2048 + tid * 8);
            ldg16(Bt + brow0 + ko + skp, Bs[hh] + tid * 8);
            ldg16(Bt + brow1 + ko + skp, Bs[hh] + 2048 + tid * 8);
        }
        __syncthreads();
        #pragma unroll
        for (int hh = 0; hh < 2; hh++) {
            bf16x8 af[4], bfr[4];
            #pragma unroll
            for (int r = 0; r < 4; r++)
                af[r] = *(const bf16x8*)(As[hh] + (wm + r * 16 + mrow) * 32 + kq);
            #pragma unroll
            for (int c = 0; c < 4; c++)
                bfr[c] = *(const bf16x8*)(Bs[hh] + (wn + c * 16 + mrow) * 32 + kq);
            #pragma unroll
            for (int r = 0; r < 4; r++)
                #pragma unroll
                for (int c = 0; c < 4; c++)
                    acc[r][c] = __builtin_amdgcn_mfma_f32_16x16x32_bf16(af[r], bfr[c], acc[r][c], 0, 0, 0);
        }
    }
    const int cr = (lane >> 4) * 4;
    const int cc = lane & 15;
    #pragma unroll
    for (int r = 0; r < 4; r++) {
        #pragma unroll
        for (int c = 0; c < 4; c++) {
            const int gc = bn + wn + c * 16 + cc;
            const float bv = BIAS ? bias[gc] : 0.0f;
            #pragma unroll
            for (int j = 0; j < 4; j++) {
                const int gr = bm + wm + r * 16 + cr + j;
                float vv = acc[r][c][j] + bv;
                if (ACT == ACT_ELU1) vv = fast_elu1(vv);
                if (ACT == ACT_GELU) vv = fast_gelu(vv);
                if (ACT == ACT_QKV)  vv = qkv_elu ? fast_elu1(vv) : vv;
                const size_t oidx = (size_t)gr * N + gc;
                if (RES) vv += resid[oidx];
                if (OUTF32) ((float*)Cout)[oidx] = vv;
                else        ((ushort_t*)Cout)[oidx] = f2b(vv);
            }
        }
    }
}

// ---------------------------------------------------------------- GEMM 256x{256,128}, 8-phase (m201-style)
// BM=256, BK=64, 512 threads = 8 waves (2M x 4N), double-buffered LDS,
// raw s_barrier (never __syncthreads -> no vmcnt(0) drain), counted vmcnt(2)
// once per K-tile, setprio(1) around each MFMA cluster.
// Bank-conflict fix: element (row,k) of each 256x64 tile is stored with
// kbyte ^= (row&1)<<6 (swap 64B k-halves on odd rows). global_load_lds dest
// stays LINEAR; the swizzle is applied to the *global source* address
// (pre-swizzled src, m173 pattern) and to the ds_read fragment address.
// Fragment read (16 rows x stride 128B, 64B window) then hits all 32 banks
// evenly: 8 accesses/bank = the 1KiB minimum.

#define G256_RD_A(BUF, FR0) \
    _Pragma("unroll") for (int _i = 0; _i < 4; ++_i) \
    _Pragma("unroll") for (int _kk = 0; _kk < 2; ++_kk) \
        af[_i][_kk] = *(const bf16x8*)(ldsb + (BUF) + aoff + (((FR0) + _i) << 11) \
                                       + (((_kk << 6) | qv16) ^ mflip))

#define G256_RD_B(BUF, FC0, CNT) \
    _Pragma("unroll") for (int _c = 0; _c < (CNT); ++_c) \
    _Pragma("unroll") for (int _kk = 0; _kk < 2; ++_kk) \
        bf[(FC0) + _c][_kk] = *(const bf16x8*)(ldsb + (BUF) + boff + (((FC0) + _c) << 11) \
                                               + (((_kk << 6) | qv16) ^ mflip))

#define G256_MFMA(AR, C0, CNT) \
    _Pragma("unroll") for (int _i = 0; _i < 4; ++_i) \
    _Pragma("unroll") for (int _c = 0; _c < (CNT); ++_c) \
    _Pragma("unroll") for (int _kk = 0; _kk < 2; ++_kk) \
        acc[(AR) + _i][(C0) + _c] = __builtin_amdgcn_mfma_f32_16x16x32_bf16( \
            af[_i][_kk], bf[(C0) + _c][_kk], acc[(AR) + _i][(C0) + _c], 0, 0, 0)

// A half H: rows H*128..H*128+127 (16KB, 2 loads/thread)
#define G256_STAGE_A(T, H) do { \
    char* _d = ldsb + (((T) & 1) ? (int)BUFSZ : 0) + ((H) << 14) + (tid << 4); \
    const ushort_t* _s = pA + (size_t)((H) * 128) * K + (size_t)(T) * 64; \
    ldg16(_s, (ushort_t*)_d); \
    ldg16(_s + (size_t)64 * K, (ushort_t*)(_d + 8192)); \
} while (0)

// B half H: rows H*(BN/2).. (BN256: 16KB, 2 loads; BN128: 8KB, 1 load)
#define G256_STAGE_B(T, H) do { \
    char* _d = ldsb + (((T) & 1) ? (int)BUFSZ : 0) + 32768 + (H) * (BN_ * 64) + (tid << 4); \
    const ushort_t* _s = pB + (size_t)((H) * (BN_ >> 1)) * K + (size_t)(T) * 64; \
    ldg16(_s, (ushort_t*)_d); \
    if (BN_ == 256) ldg16(_s + (size_t)64 * K, (ushort_t*)(_d + 8192)); \
} while (0)

#define G256_BARW() do { \
    __builtin_amdgcn_s_barrier(); \
    asm volatile("s_waitcnt lgkmcnt(0)" ::: "memory"); \
    __builtin_amdgcn_sched_barrier(0); \
    __builtin_amdgcn_s_setprio(1); \
} while (0)

#define G256_ENDP() do { \
    __builtin_amdgcn_s_setprio(0); \
    __builtin_amdgcn_s_barrier(); \
} while (0)

template<int BN_, int ACT, bool BIAS, bool RES, bool OUTF32>
__global__ void __launch_bounds__(512, 2)
gemm256(const ushort_t* __restrict__ A, const ushort_t* __restrict__ Bt,
        const float* __restrict__ bias, const float* __restrict__ resid,
        void* __restrict__ Cout, int M, int N, int K)
{
    constexpr int NF    = BN_ / 64;              // col-frags per wave (4 or 2)
    constexpr int BUFSZ = 32768 + BN_ * 128;     // A 32KB + B BN*64*2B per buffer
    __shared__ __align__(16) char ldsb[2 * BUFSZ];

    const int tid  = threadIdx.x;
    const int lane = tid & 63, wave = tid >> 6;
    const int wm_idx = wave >> 2, wn_idx = wave & 3;
    const int bm = blockIdx.x * 256, bn = blockIdx.y * BN_;

    // staging: thread covers row r0 (+64 for 2nd call), 16B at pre-swizzled col
    const int r0  = tid >> 3;
    const int kbs = ((tid & 7) << 4) ^ ((r0 & 1) << 6);     // byte col, inverse-swizzled
    const ushort_t* pA = A  + (size_t)(bm + r0) * K + (kbs >> 1);
    const ushort_t* pB = Bt + (size_t)(bn + r0) * K + (kbs >> 1);

    // fragment reads
    const int m     = lane & 15;
    const int qv16  = (lane >> 4) << 4;          // 0,16,32,48 bytes
    const int mflip = (m & 1) << 6;              // swizzle on read
    const int aoff  = (wm_idx * 128 + m) << 7;
    const int boff  = 32768 + ((wn_idx * (BN_ >> 2) + m) << 7);

    f32x4  acc[8][NF] = {};
    bf16x8 af[4][2], bf[NF][2];

    const int NT    = K >> 6;                    // K % 128 == 0 -> NT even
    const int niter = NT >> 1;

    // prologue: tile0 fully + tile1 A-half0; wait so tile0 landed (t1h0 may fly)
    G256_STAGE_A(0, 0); G256_STAGE_A(0, 1);
    G256_STAGE_B(0, 0); G256_STAGE_B(0, 1);
    G256_STAGE_A(1, 0);
    asm volatile("s_waitcnt vmcnt(2)" ::: "memory");
    __builtin_amdgcn_s_barrier();

    for (int it = 0; it < niter; ++it) {
        const int  t    = it << 1;
        const bool more = (it + 1) < niter;

        // ---- tile t (buf 0): phases 0-3 ----
        G256_RD_A(0, 0); G256_RD_B(0, 0, NF / 2);
        G256_STAGE_A(t + 1, 1);
        G256_BARW(); G256_MFMA(0, 0, NF / 2); G256_ENDP();

        G256_RD_B(0, NF / 2, NF / 2);
        G256_STAGE_B(t + 1, 0);
        G256_BARW(); G256_MFMA(0, NF / 2, NF / 2); G256_ENDP();

        G256_RD_A(0, 4);
        G256_STAGE_B(t + 1, 1);
        G256_BARW(); G256_MFMA(4, 0, NF / 2); G256_ENDP();

        if (more) G256_STAGE_A(t + 2, 0);        // buf0 reads done (ph2 barrier)
        G256_BARW(); G256_MFMA(4, NF / 2, NF / 2);
        __builtin_amdgcn_s_setprio(0);
        if (more) asm volatile("s_waitcnt vmcnt(2)" ::: "memory");   // tile t+1 landed
        else      asm volatile("s_waitcnt vmcnt(0)" ::: "memory");
        __builtin_amdgcn_s_barrier();

        // ---- tile t+1 (buf 1): phases 4-7 ----
        G256_RD_A(BUFSZ, 0); G256_RD_B(BUFSZ, 0, NF / 2);
        if (more) G256_STAGE_A(t + 2, 1);
        G256_BARW(); G256_MFMA(0, 0, NF / 2); G256_ENDP();

        G256_RD_B(BUFSZ, NF / 2, NF / 2);
        if (more) G256_STAGE_B(t + 2, 0);
        G256_BARW(); G256_MFMA(0, NF / 2, NF / 2); G256_ENDP();

        G256_RD_A(BUFSZ, 4);
        if (more) G256_STAGE_B(t + 2, 1);
        G256_BARW(); G256_MFMA(4, 0, NF / 2); G256_ENDP();

        if (more) G256_STAGE_A(t + 3, 0);        // buf1 reads done (ph6 barrier)
        G256_BARW(); G256_MFMA(4, NF / 2, NF / 2);
        __builtin_amdgcn_s_setprio(0);
        if (more) asm volatile("s_waitcnt vmcnt(2)" ::: "memory");   // tile t+2 landed
        else      asm volatile("s_waitcnt vmcnt(0)" ::: "memory");
        __builtin_amdgcn_s_barrier();
    }

    // epilogue: C/D layout col=lane&15, row=(lane>>4)*4+reg [m89/m91]
    const int cr   = (lane >> 4) << 2;
    const int ccol = lane & 15;
    #pragma unroll
    for (int fr = 0; fr < 8; ++fr) {
        #pragma unroll
        for (int fc = 0; fc < NF; ++fc) {
            const int gc = bn + wn_idx * (BN_ >> 2) + fc * 16 + ccol;
            const float bv = BIAS ? bias[gc] : 0.0f;
            #pragma unroll
            for (int j = 0; j < 4; ++j) {
                const int gr = bm + wm_idx * 128 + fr * 16 + cr + j;
                float vv = acc[fr][fc][j] + bv;
                if (ACT == ACT_ELU1) vv = fast_elu1(vv);
                if (ACT == ACT_GELU) vv = fast_gelu(vv);
                if (ACT == ACT_QKV)  vv = (bn < 2048) ? fast_elu1(vv) : vv;
                const size_t oidx = (size_t)gr * N + gc;
                if (RES) vv += resid[oidx];
                if (OUTF32) ((float*)Cout)[oidx] = vv;
                else        ((ushort_t*)Cout)[oidx] = f2b(vv);
            }
        }
    }
    (void)M;
}

// ---------------------------------------------------------------- attention
// qkv buffer row stride = QSTR; K at col 1024, V at col 2048
__global__ void __launch_bounds__(256)
attn_phase1(const ushort_t* __restrict__ qkv,
            float* __restrict__ P, float* __restrict__ Ksum)
{
    const int c = blockIdx.x, h = blockIdx.y, b = blockIdx.z;
    __shared__ ushort_t Ks[64][68], Vs[64][68];
    const int tid = threadIdx.x;
    const size_t rowbase = (size_t)b * SEQ + c * 64;
    #pragma unroll
    for (int i = 0; i < 4; i++) {
        const int lin = tid + 256 * i;          // (t, d4) over 64x16
        const int t = lin >> 4, d4 = (lin & 15) * 4;
        const size_t gidx = (rowbase + t) * QSTR + h * HD + d4;
        *(uint2*)&Ks[t][d4] = *(const uint2*)(qkv + 1024 + gidx);
        *(uint2*)&Vs[t][d4] = *(const uint2*)(qkv + 2048 + gidx);
    }
    __syncthreads();
    const int d0 = (tid >> 4) * 4, e0 = (tid & 15) * 4;
    float acc[4][4] = {};
    for (int t = 0; t < 64; t++) {
        float kf[4], vf[4];
        unpack4(*(const uint2*)&Ks[t][d0], kf);
        unpack4(*(const uint2*)&Vs[t][e0], vf);
        #pragma unroll
        for (int i = 0; i < 4; i++)
            #pragma unroll
            for (int j = 0; j < 4; j++)
                acc[i][j] += kf[i] * vf[j];
    }
    const size_t pbase = (((size_t)b * NH + h) * NCHUNK + c) * 4096;
    #pragma unroll
    for (int i = 0; i < 4; i++) {
        float4 o; o.x = acc[i][0]; o.y = acc[i][1]; o.z = acc[i][2]; o.w = acc[i][3];
        *(float4*)(P + pbase + (size_t)(d0 + i) * 64 + e0) = o;
    }
    if (tid < 64) {
        float a = 0.0f;
        for (int t = 0; t < 64; t++) a += b2f(Ks[t][tid]);
        Ksum[(((size_t)b * NH + h) * NCHUNK + c) * 64 + tid] = a;
    }
}

// phase 1b: exclusive prefix over chunks, column-parallel.
__global__ void __launch_bounds__(256)
attn_prefix(float* __restrict__ P, float* __restrict__ Ksum)
{
    const int bh = blockIdx.y;
    const int e  = blockIdx.x * 256 + threadIdx.x;
    const size_t base = (size_t)bh * NCHUNK * 4096 + e;
    float acc = 0.0f;
    #pragma unroll
    for (int c = 0; c < NCHUNK; c++) {
        const float t = P[base + (size_t)c * 4096];
        P[base + (size_t)c * 4096] = acc;
        acc += t;
    }
    if (blockIdx.x == 0 && threadIdx.x < 64) {
        const size_t kb = (size_t)bh * NCHUNK * 64 + threadIdx.x;
        float a = 0.0f;
        #pragma unroll
        for (int c = 0; c < NCHUNK; c++) {
            const float t = Ksum[kb + c * 64];
            Ksum[kb + c * 64] = a;
            a += t;
        }
    }
}

// phase 2: out = (Q@M_prev + causal(QK^T)@V) / (Q@ksum_prev + rowsum(S) + 1e-6)
__global__ void __launch_bounds__(256)
attn_phase2(const ushort_t* __restrict__ qkv, const float* __restrict__ P,
            const float* __restrict__ Ksum, ushort_t* __restrict__ Out)
{
    const int c = blockIdx.x, h = blockIdx.y, b = blockIdx.z;
    const int tid = threadIdx.x;
    __shared__ ushort_t Qs[64][68], KsB[64][68], VsB[64][68];
    __shared__ float S[64][68];
    __shared__ float Mp[64][64];
    __shared__ float kp[64];
    __shared__ float partial[4][64];
    const size_t rowbase = (size_t)b * SEQ + c * 64;
    const size_t pbase = (((size_t)b * NH + h) * NCHUNK + c) * 4096;
    #pragma unroll
    for (int i = 0; i < 4; i++) {
        const int lin = tid + 256 * i;          // (t, d4) over 64x16
        const int t = lin >> 4, d4 = (lin & 15) * 4;
        const size_t gidx = (rowbase + t) * QSTR + h * HD + d4;
        *(uint2*)&Qs[t][d4]  = *(const uint2*)(qkv + gidx);
        *(uint2*)&KsB[t][d4] = *(const uint2*)(qkv + 1024 + gidx);
        *(uint2*)&VsB[t][d4] = *(const uint2*)(qkv + 2048 + gidx);
        *(float4*)&Mp[t][d4] = *(const float4*)(P + pbase + lin * 4);
    }
    if (tid < 64) kp[tid] = Ksum[(((size_t)b * NH + h) * NCHUNK + c) * 64 + tid];
    __syncthreads();

    const int t0 = (tid >> 4) * 4;
    const int c0 = (tid & 15) * 4;              // ii-block for S phase, e-block later

    // S = causal(Q K^T); masked entries written as 0
    {
        float accS[4][4] = {};
        for (int d4 = 0; d4 < 64; d4 += 4) {
            float qf[4][4], kf[4][4];
            #pragma unroll
            for (int i = 0; i < 4; i++) {
                unpack4(*(const uint2*)&Qs[t0 + i][d4], qf[i]);
                unpack4(*(const uint2*)&KsB[c0 + i][d4], kf[i]);
            }
            #pragma unroll
            for (int i = 0; i < 4; i++)
                #pragma unroll
                for (int j = 0; j < 4; j++)
                    #pragma unroll
                    for (int dd = 0; dd < 4; dd++)
                        accS[i][j] += qf[i][dd] * kf[j][dd];
        }
        #pragma unroll
        for (int i = 0; i < 4; i++) {
            float4 sv;
            sv.x = (c0 + 0 <= t0 + i) ? accS[i][0] : 0.0f;
            sv.y = (c0 + 1 <= t0 + i) ? accS[i][1] : 0.0f;
            sv.z = (c0 + 2 <= t0 + i) ? accS[i][2] : 0.0f;
            sv.w = (c0 + 3 <= t0 + i) ? accS[i][3] : 0.0f;
            *(float4*)&S[t0 + i][c0] = sv;
        }
    }
    __syncthreads();

    // den partials: quarter-range per thread
    {
        const int t = tid & 63, q = tid >> 6;
        const int base = q * 16;
        float a = 0.0f;
        #pragma unroll
        for (int ii = 0; ii < 16; ii++) a += S[t][base + ii];
        #pragma unroll
        for (int d = 0; d < 16; d++) a += b2f(Qs[t][base + d]) * kp[base + d];
        partial[q][t] = a;
    }
    __syncthreads();

    // out = S@V + Q@Mp, then /den
    float acc[4][4] = {};
    for (int ii = 0; ii < 64; ii++) {
        float vf[4];
        unpack4(*(const uint2*)&VsB[ii][c0], vf);
        #pragma unroll
        for (int i = 0; i < 4; i++) {
            const float s = S[t0 + i][ii];
            #pragma unroll
            for (int j = 0; j < 4; j++) acc[i][j] += s * vf[j];
        }
    }
    for (int d = 0; d < 64; d++) {
        const float4 mp = *(const float4*)&Mp[d][c0];
        #pragma unroll
        for (int i = 0; i < 4; i++) {
            const float qv = b2f(Qs[t0 + i][d]);
            acc[i][0] += qv * mp.x; acc[i][1] += qv * mp.y;
            acc[i][2] += qv * mp.z; acc[i][3] += qv * mp.w;
        }
    }
    #pragma unroll
    for (int i = 0; i < 4; i++) {
        const float dent = partial[0][t0 + i] + partial[1][t0 + i] +
                           partial[2][t0 + i] + partial[3][t0 + i] + 1e-6f;
        const float r = 1.0f / dent;
        ushort_t o[4];
        #pragma unroll
        for (int j = 0; j < 4; j++) o[j] = f2b(acc[i][j] * r);
        uint2 u2;
        u2.x = (unsigned int)o[0] | ((unsigned int)o[1] << 16);
        u2.y = (unsigned int)o[2] | ((unsigned int)o[3] << 16);
        *(uint2*)(Out + (rowbase + t0 + i) * DIM + h * HD + c0) = u2;
    }
}

// ---------------------------------------------------------------- launcher
extern "C" void kernel_launch(void* const* d_in, const int* in_sizes, int n_in,
                              void* d_out, int out_size, void* d_ws, size_t ws_size,
                              hipStream_t stream)
{
    const float* x      = (const float*)d_in[0];
    const float* Wq     = (const float*)d_in[1];
    const float* Wk     = (const float*)d_in[2];
    const float* Wv     = (const float*)d_in[3];
    const float* Wo     = (const float*)d_in[4];
    const float* ln1g   = (const float*)d_in[5];
    const float* ln1b   = (const float*)d_in[6];
    const float* ln2g   = (const float*)d_in[7];
    const float* ln2b   = (const float*)d_in[8];
    const float* cw1    = (const float*)d_in[9];
    const float* cb1    = (const float*)d_in[10];
    const float* cw2    = (const float*)d_in[11];
    const float* cb2    = (const float*)d_in[12];

    char* ws = (char*)d_ws;
    ushort_t* h     = (ushort_t*)(ws + OFF_H);
    ushort_t* qkv   = (ushort_t*)(ws + OFF_Q);
    float*    Pb    = (float*)(ws + OFF_P);
    float*    ksb   = (float*)(ws + OFF_KS);
    float*    x1    = (float*)(ws + OFF_X1);
    ushort_t* wqkvt = (ushort_t*)(ws + OFF_WQT);
    ushort_t* wot   = (ushort_t*)(ws + OFF_WOT);
    ushort_t* w1t   = (ushort_t*)(ws + OFF_W1T);
    ushort_t* w2t   = (ushort_t*)(ws + OFF_W2T);
    ushort_t* hid   = (ushort_t*)(ws + OFF_HIDB);
    float*    outp  = (float*)d_out;

    const dim3 tb(32, 8);
    // fused qkv weight^T: [3072][1024]
    transpose_f32_bf16<<<dim3(32, 32), tb, 0, stream>>>(Wq, wqkvt,                   DIM, DIM);
    transpose_f32_bf16<<<dim3(32, 32), tb, 0, stream>>>(Wk, wqkvt + 1024 * 1024,     DIM, DIM);
    transpose_f32_bf16<<<dim3(32, 32), tb, 0, stream>>>(Wv, wqkvt + 2 * 1024 * 1024, DIM, DIM);
    transpose_f32_bf16<<<dim3(32, 32), tb, 0, stream>>>(Wo, wot, DIM, DIM);
    for (int l = 0; l < 3; l++) {
        transpose_f32_bf16<<<dim3(128, 32), tb, 0, stream>>>(cw1 + (size_t)l * DIM * HID,
                                                             w1t + (size_t)l * HID * DIM, DIM, HID);
        transpose_f32_bf16<<<dim3(32, 128), tb, 0, stream>>>(cw2 + (size_t)l * HID * DIM,
                                                             w2t + (size_t)l * DIM * HID, HID, DIM);
    }

    ln_fwd<<<MROWS, 256, 0, stream>>>(x, ln1g, ln1b, h);

    // fused Q|K|V projection: [8192][3072], elu+1 on first 2048 cols
    // BN=128 -> 32x24 = 768 wg = 3 full waves of 256 CUs
    gemm256<128, ACT_QKV, false, false, false><<<dim3(32, 24), 512, 0, stream>>>(
        h, wqkvt, nullptr, nullptr, qkv, MROWS, QSTR, DIM);

    attn_phase1<<<dim3(NCHUNK, NH, NB), 256, 0, stream>>>(qkv, Pb, ksb);
    attn_prefix<<<dim3(16, 64), 256, 0, stream>>>(Pb, ksb);
    attn_phase2<<<dim3(NCHUNK, NH, NB), 256, 0, stream>>>(qkv, Pb, ksb, h);  // h := attn out

    // Wo: N=1024, BN=128 -> 32x8 = 256 wg (exact fill)
    gemm256<128, ACT_NONE, false, true, true><<<dim3(32, 8), 512, 0, stream>>>(
        h, wot, nullptr, x, x1, MROWS, DIM, DIM);

    ln_fwd<<<MROWS, 256, 0, stream>>>(x1, ln2g, ln2b, h);

    const ushort_t* cur = h;
    for (int l = 0; l < 3; l++) {
        // w1: N=4096, BN=256 -> 32x16 = 512 wg = 2 full waves
        gemm256<256, ACT_GELU, true, false, false><<<dim3(32, 16), 512, 0, stream>>>(
            cur, w1t + (size_t)l * HID * DIM, cb1 + (size_t)l * HID, nullptr, hid, MROWS, HID, DIM);
        if (l < 2) {
            // w2: N=1024 K=4096, BN=128 -> 256 wg (exact fill)
            gemm256<128, ACT_NONE, true, false, false><<<dim3(32, 8), 512, 0, stream>>>(
                hid, w2t + (size_t)l * DIM * HID, cb2 + (size_t)l * DIM, nullptr, h, MROWS, DIM, HID);
            cur = h;
        } else {
            gemm256<128, ACT_NONE, true, true, true><<<dim3(32, 8), 512, 0, stream>>>(
                hid, w2t + (size_t)l * DIM * HID, cb2 + (size_t)l * DIM, x1, outp, MROWS, DIM, HID);
        }
    }
    (void)in_sizes; (void)n_in; (void)out_size; (void)ws_size;
}

// Round 2
// 848.936 us; speedup vs baseline: 1.2565x; 1.2565x over previous
//
#include <hip/hip_runtime.h>
#include <stdint.h>
#include <math.h>

// ---------------------------------------------------------------- constants
#define DIM     1024
#define HID     4096
#define SEQ     2048
#define NB      4
#define NH      16
#define HD      64
#define NCHUNK  32          // SEQ / 64
#define MROWS   8192        // NB * SEQ
#define QSTR    3072        // fused qkv row stride

typedef unsigned short ushort_t;
typedef __attribute__((ext_vector_type(8))) short bf16x8;
typedef __attribute__((ext_vector_type(4))) float f32x4;

// ws layout (bytes) — peak ~193.5 MB, proven non-faulting
#define OFF_H    ((size_t)0)            // bf16 [8192][1024]
#define OFF_Q    ((size_t)16777216)     // bf16 [8192][3072] fused qkv
#define OFF_P    ((size_t)67108864)     // f32 [64][32][4096]
#define OFF_KS   ((size_t)100663296)    // f32 [64][32][64]
#define OFF_X1   ((size_t)101187584)    // f32 [8192][1024]
#define OFF_WQT  ((size_t)134742016)    // bf16 [3072][1024] fused qkv weights^T
#define OFF_WOT  ((size_t)141033472)
#define OFF_W1T  ((size_t)143130624)    // 3 x bf16 [4096][1024]
#define OFF_W2T  ((size_t)168296448)    // 3 x bf16 [1024][4096]
#define OFF_HIDB OFF_Q + 16777216       // bf16 [8192][4096]: spans old K,V,P (dead at CMS time)

__device__ __forceinline__ float b2f(ushort_t u) {
    return __uint_as_float(((unsigned int)u) << 16);
}
__device__ __forceinline__ ushort_t f2b(float f) {
    unsigned int u = __float_as_uint(f);
    u += 0x7FFFu + ((u >> 16) & 1u);          // round-to-nearest-even
    return (ushort_t)(u >> 16);
}
__device__ __forceinline__ void unpack4(uint2 u, float* f) {
    f[0] = __uint_as_float(u.x << 16);
    f[1] = __uint_as_float(u.x & 0xffff0000u);
    f[2] = __uint_as_float(u.y << 16);
    f[3] = __uint_as_float(u.y & 0xffff0000u);
}
// gelu(tanh form) == x*sigmoid(2z); ~7 VALU ops vs ~40 for libm tanhf
__device__ __forceinline__ float fast_gelu(float x) {
    const float u = x * (1.5957691216057308f + 0.07135481627f * x * x);  // 2z
    const float e = exp2f(-1.4426950408889634f * u);
    return x * __builtin_amdgcn_rcpf(1.0f + e);
}
__device__ __forceinline__ float fast_elu1(float x) {
    return x > 0.0f ? x + 1.0f : exp2f(1.4426950408889634f * x);
}
// async 16B global->LDS DMA; LDS dest must be wave-uniform base + lane*16 [m97/m104]
__device__ __forceinline__ void ldg16(const ushort_t* g, ushort_t* l) {
    __builtin_amdgcn_global_load_lds(
        (const __attribute__((address_space(1))) void*)g,
        (__attribute__((address_space(3))) void*)l, 16, 0, 0);
}

// ---------------------------------------------------------------- transpose (f32 -> bf16)
__global__ void __launch_bounds__(256)
transpose_f32_bf16(const float* __restrict__ src, ushort_t* __restrict__ dst, int R, int C)
{
    __shared__ float t[32][33];
    const int bx = blockIdx.x * 32;
    const int by = blockIdx.y * 32;
    const int tx = threadIdx.x, ty = threadIdx.y;
    #pragma unroll
    for (int i = ty; i < 32; i += 8)
        t[i][tx] = src[(size_t)(by + i) * C + bx + tx];
    __syncthreads();
    #pragma unroll
    for (int i = ty; i < 32; i += 8)
        dst[(size_t)(bx + i) * R + by + tx] = f2b(t[tx][i]);
}

// ---------------------------------------------------------------- layernorm (f32 in, bf16 out)
__global__ void __launch_bounds__(256)
ln_fwd(const float* __restrict__ xin, const float* __restrict__ g,
       const float* __restrict__ be, ushort_t* __restrict__ out)
{
    const int row = blockIdx.x, tid = threadIdx.x;
    const float4 f = ((const float4*)(xin + (size_t)row * DIM))[tid];
    float v[4] = {f.x, f.y, f.z, f.w};
    float s  = v[0] + v[1] + v[2] + v[3];
    float ss = v[0]*v[0] + v[1]*v[1] + v[2]*v[2] + v[3]*v[3];
    #pragma unroll
    for (int off = 32; off; off >>= 1) {
        s  += __shfl_down(s, off);
        ss += __shfl_down(ss, off);
    }
    __shared__ float red[2][4];
    const int wave = tid >> 6, lane = tid & 63;
    if (lane == 0) { red[0][wave] = s; red[1][wave] = ss; }
    __syncthreads();
    s  = red[0][0] + red[0][1] + red[0][2] + red[0][3];
    ss = red[1][0] + red[1][1] + red[1][2] + red[1][3];
    const float mean = s * (1.0f / DIM);
    const float var  = ss * (1.0f / DIM) - mean * mean;
    const float rstd = rsqrtf(var + 1e-5f);
    ushort_t o[4];
    #pragma unroll
    for (int i = 0; i < 4; i++) {
        const int col = tid * 4 + i;
        o[i] = f2b((v[i] - mean) * rstd * g[col] + be[col]);
    }
    uint2 u2;
    u2.x = (unsigned int)o[0] | ((unsigned int)o[1] << 16);
    u2.y = (unsigned int)o[2] | ((unsigned int)o[3] << 16);
    *(uint2*)(out + (size_t)row * DIM + tid * 4) = u2;
}

#define ACT_NONE 0
#define ACT_ELU1 1
#define ACT_GELU 2
#define ACT_QKV  3   // cols < 2048 -> elu+1 (Q,K); cols >= 2048 -> none (V). block-uniform.

// ---------------------------------------------------------------- GEMM 256x{256,128}, 8-phase (m201-style)
// BM=256, BK=64, 512 threads = 8 waves (2M x 4N), double-buffered LDS,
// raw s_barrier (never __syncthreads -> no vmcnt(0) drain), counted vmcnt(2)
// once per K-tile, setprio(1) around each MFMA cluster.
// Bank-conflict fix (round-1): tile rows are 128B, banks alias every 128B, so
// a fragment ds_read_b128 has 16 lanes (m=0..15) hitting the SAME 16B col-slot
// of 16 different rows -> same banks. Swizzle col bits 4-6 with row bits 0-2:
//   LDS[(r, c)] = G[(r, c ^ ((r&7)<<4))]
// Every consecutive-8-lane beat then covers all eight 16B slots of the 128B
// bank span exactly once -> conflict-free. (round-0's (row&1)<<6 only split
// lanes 2 ways -> 8-way conflict, 18.9M SQ_LDS_BANK_CONFLICT, the regression.)
// global_load_lds dest stays LINEAR; swizzle applied to the *global source*
// address (m173 pattern) and to the ds_read fragment address — same involution
// both sides [rule 21]. All staged row offsets (64,128) are multiples of 8, so
// the per-thread baked-in source swizzle is valid for every STAGE call.

#define G256_RD_A(BUF, FR0) \
    _Pragma("unroll") for (int _i = 0; _i < 4; ++_i) \
    _Pragma("unroll") for (int _kk = 0; _kk < 2; ++_kk) \
        af[_i][_kk] = *(const bf16x8*)(ldsb + (BUF) + aoff + (((FR0) + _i) << 11) \
                                       + (((_kk << 6) | qv16) ^ mflip))

#define G256_RD_B(BUF, FC0, CNT) \
    _Pragma("unroll") for (int _c = 0; _c < (CNT); ++_c) \
    _Pragma("unroll") for (int _kk = 0; _kk < 2; ++_kk) \
        bf[(FC0) + _c][_kk] = *(const bf16x8*)(ldsb + (BUF) + boff + (((FC0) + _c) << 11) \
                                               + (((_kk << 6) | qv16) ^ mflip))

#define G256_MFMA(AR, C0, CNT) \
    _Pragma("unroll") for (int _i = 0; _i < 4; ++_i) \
    _Pragma("unroll") for (int _c = 0; _c < (CNT); ++_c) \
    _Pragma("unroll") for (int _kk = 0; _kk < 2; ++_kk) \
        acc[(AR) + _i][(C0) + _c] = __builtin_amdgcn_mfma_f32_16x16x32_bf16( \
            af[_i][_kk], bf[(C0) + _c][_kk], acc[(AR) + _i][(C0) + _c], 0, 0, 0)

// A half H: rows H*128..H*128+127 (16KB, 2 loads/thread)
#define G256_STAGE_A(T, H) do { \
    char* _d = ldsb + (((T) & 1) ? (int)BUFSZ : 0) + ((H) << 14) + (tid << 4); \
    const ushort_t* _s = pA + (size_t)((H) * 128) * K + (size_t)(T) * 64; \
    ldg16(_s, (ushort_t*)_d); \
    ldg16(_s + (size_t)64 * K, (ushort_t*)(_d + 8192)); \
} while (0)

// B half H: rows H*(BN/2).. (BN256: 16KB, 2 loads; BN128: 8KB, 1 load)
#define G256_STAGE_B(T, H) do { \
    char* _d = ldsb + (((T) & 1) ? (int)BUFSZ : 0) + 32768 + (H) * (BN_ * 64) + (tid << 4); \
    const ushort_t* _s = pB + (size_t)((H) * (BN_ >> 1)) * K + (size_t)(T) * 64; \
    ldg16(_s, (ushort_t*)_d); \
    if (BN_ == 256) ldg16(_s + (size_t)64 * K, (ushort_t*)(_d + 8192)); \
} while (0)

#define G256_BARW() do { \
    __builtin_amdgcn_s_barrier(); \
    asm volatile("s_waitcnt lgkmcnt(0)" ::: "memory"); \
    __builtin_amdgcn_sched_barrier(0); \
    __builtin_amdgcn_s_setprio(1); \
} while (0)

#define G256_ENDP() do { \
    __builtin_amdgcn_s_setprio(0); \
    __builtin_amdgcn_s_barrier(); \
} while (0)

template<int BN_, int ACT, bool BIAS, bool RES, bool OUTF32>
__global__ void __launch_bounds__(512, 2)
gemm256(const ushort_t* __restrict__ A, const ushort_t* __restrict__ Bt,
        const float* __restrict__ bias, const float* __restrict__ resid,
        void* __restrict__ Cout, int M, int N, int K)
{
    constexpr int NF    = BN_ / 64;              // col-frags per wave (4 or 2)
    constexpr int BUFSZ = 32768 + BN_ * 128;     // A 32KB + B BN*64*2B per buffer
    __shared__ __align__(16) char ldsb[2 * BUFSZ];

    const int tid  = threadIdx.x;
    const int lane = tid & 63, wave = tid >> 6;
    const int wm_idx = wave >> 2, wn_idx = wave & 3;
    const int bm = blockIdx.x * 256, bn = blockIdx.y * BN_;

    // staging: thread covers row r0 (+64/128 for later calls), 16B at
    // pre-swizzled col: c_global = c_lds ^ ((r0&7)<<4)
    const int r0  = tid >> 3;
    const int kbs = (((tid & 7) ^ (r0 & 7)) << 4);          // byte col, inverse-swizzled
    const ushort_t* pA = A  + (size_t)(bm + r0) * K + (kbs >> 1);
    const ushort_t* pB = Bt + (size_t)(bn + r0) * K + (kbs >> 1);

    // fragment reads
    const int m     = lane & 15;
    const int qv16  = (lane >> 4) << 4;          // 0,16,32,48 bytes
    const int mflip = (m & 7) << 4;              // swizzle on read (row bits 0-2 -> col bits 4-6)
    const int aoff  = (wm_idx * 128 + m) << 7;
    const int boff  = 32768 + ((wn_idx * (BN_ >> 2) + m) << 7);

    f32x4  acc[8][NF] = {};
    bf16x8 af[4][2], bf[NF][2];

    const int NT    = K >> 6;                    // K % 128 == 0 -> NT even
    const int niter = NT >> 1;

    // prologue: tile0 fully + tile1 A-half0; wait so tile0 landed (t1h0 may fly)
    G256_STAGE_A(0, 0); G256_STAGE_A(0, 1);
    G256_STAGE_B(0, 0); G256_STAGE_B(0, 1);
    G256_STAGE_A(1, 0);
    asm volatile("s_waitcnt vmcnt(2)" ::: "memory");
    __builtin_amdgcn_s_barrier();

    for (int it = 0; it < niter; ++it) {
        const int  t    = it << 1;
        const bool more = (it + 1) < niter;

        // ---- tile t (buf 0): phases 0-3 ----
        G256_RD_A(0, 0); G256_RD_B(0, 0, NF / 2);
        G256_STAGE_A(t + 1, 1);
        G256_BARW(); G256_MFMA(0, 0, NF / 2); G256_ENDP();

        G256_RD_B(0, NF / 2, NF / 2);
        G256_STAGE_B(t + 1, 0);
        G256_BARW(); G256_MFMA(0, NF / 2, NF / 2); G256_ENDP();

        G256_RD_A(0, 4);
        G256_STAGE_B(t + 1, 1);
        G256_BARW(); G256_MFMA(4, 0, NF / 2); G256_ENDP();

        if (more) G256_STAGE_A(t + 2, 0);        // buf0 reads done (ph2 barrier)
        G256_BARW(); G256_MFMA(4, NF / 2, NF / 2);
        __builtin_amdgcn_s_setprio(0);
        if (more) asm volatile("s_waitcnt vmcnt(2)" ::: "memory");   // tile t+1 landed
        else      asm volatile("s_waitcnt vmcnt(0)" ::: "memory");
        __builtin_amdgcn_s_barrier();

        // ---- tile t+1 (buf 1): phases 4-7 ----
        G256_RD_A(BUFSZ, 0); G256_RD_B(BUFSZ, 0, NF / 2);
        if (more) G256_STAGE_A(t + 2, 1);
        G256_BARW(); G256_MFMA(0, 0, NF / 2); G256_ENDP();

        G256_RD_B(BUFSZ, NF / 2, NF / 2);
        if (more) G256_STAGE_B(t + 2, 0);
        G256_BARW(); G256_MFMA(0, NF / 2, NF / 2); G256_ENDP();

        G256_RD_A(BUFSZ, 4);
        if (more) G256_STAGE_B(t + 2, 1);
        G256_BARW(); G256_MFMA(4, 0, NF / 2); G256_ENDP();

        if (more) G256_STAGE_A(t + 3, 0);        // buf1 reads done (ph6 barrier)
        G256_BARW(); G256_MFMA(4, NF / 2, NF / 2);
        __builtin_amdgcn_s_setprio(0);
        if (more) asm volatile("s_waitcnt vmcnt(2)" ::: "memory");   // tile t+2 landed
        else      asm volatile("s_waitcnt vmcnt(0)" ::: "memory");
        __builtin_amdgcn_s_barrier();
    }

    // epilogue: C/D layout col=lane&15, row=(lane>>4)*4+reg [m89/m91]
    const int cr   = (lane >> 4) << 2;
    const int ccol = lane & 15;
    #pragma unroll
    for (int fr = 0; fr < 8; ++fr) {
        #pragma unroll
        for (int fc = 0; fc < NF; ++fc) {
            const int gc = bn + wn_idx * (BN_ >> 2) + fc * 16 + ccol;
            const float bv = BIAS ? bias[gc] : 0.0f;
            #pragma unroll
            for (int j = 0; j < 4; ++j) {
                const int gr = bm + wm_idx * 128 + fr * 16 + cr + j;
                float vv = acc[fr][fc][j] + bv;
                if (ACT == ACT_ELU1) vv = fast_elu1(vv);
                if (ACT == ACT_GELU) vv = fast_gelu(vv);
                if (ACT == ACT_QKV)  vv = (bn < 2048) ? fast_elu1(vv) : vv;
                const size_t oidx = (size_t)gr * N + gc;
                if (RES) vv += resid[oidx];
                if (OUTF32) ((float*)Cout)[oidx] = vv;
                else        ((ushort_t*)Cout)[oidx] = f2b(vv);
            }
        }
    }
    (void)M;
}

// ---------------------------------------------------------------- attention
// qkv buffer row stride = QSTR; K at col 1024, V at col 2048
__global__ void __launch_bounds__(256)
attn_phase1(const ushort_t* __restrict__ qkv,
            float* __restrict__ P, float* __restrict__ Ksum)
{
    const int c = blockIdx.x, h = blockIdx.y, b = blockIdx.z;
    __shared__ ushort_t Ks[64][68], Vs[64][68];
    const int tid = threadIdx.x;
    const size_t rowbase = (size_t)b * SEQ + c * 64;
    #pragma unroll
    for (int i = 0; i < 4; i++) {
        const int lin = tid + 256 * i;          // (t, d4) over 64x16
        const int t = lin >> 4, d4 = (lin & 15) * 4;
        const size_t gidx = (rowbase + t) * QSTR + h * HD + d4;
        *(uint2*)&Ks[t][d4] = *(const uint2*)(qkv + 1024 + gidx);
        *(uint2*)&Vs[t][d4] = *(const uint2*)(qkv + 2048 + gidx);
    }
    __syncthreads();
    const int d0 = (tid >> 4) * 4, e0 = (tid & 15) * 4;
    float acc[4][4] = {};
    for (int t = 0; t < 64; t++) {
        float kf[4], vf[4];
        unpack4(*(const uint2*)&Ks[t][d0], kf);
        unpack4(*(const uint2*)&Vs[t][e0], vf);
        #pragma unroll
        for (int i = 0; i < 4; i++)
            #pragma unroll
            for (int j = 0; j < 4; j++)
                acc[i][j] += kf[i] * vf[j];
    }
    const size_t pbase = (((size_t)b * NH + h) * NCHUNK + c) * 4096;
    #pragma unroll
    for (int i = 0; i < 4; i++) {
        float4 o; o.x = acc[i][0]; o.y = acc[i][1]; o.z = acc[i][2]; o.w = acc[i][3];
        *(float4*)(P + pbase + (size_t)(d0 + i) * 64 + e0) = o;
    }
    if (tid < 64) {
        float a = 0.0f;
        for (int t = 0; t < 64; t++) a += b2f(Ks[t][tid]);
        Ksum[(((size_t)b * NH + h) * NCHUNK + c) * 64 + tid] = a;
    }
}

// phase 1b: exclusive prefix over chunks, column-parallel.
__global__ void __launch_bounds__(256)
attn_prefix(float* __restrict__ P, float* __restrict__ Ksum)
{
    const int bh = blockIdx.y;
    const int e  = blockIdx.x * 256 + threadIdx.x;
    const size_t base = (size_t)bh * NCHUNK * 4096 + e;
    float acc = 0.0f;
    #pragma unroll
    for (int c = 0; c < NCHUNK; c++) {
        const float t = P[base + (size_t)c * 4096];
        P[base + (size_t)c * 4096] = acc;
        acc += t;
    }
    if (blockIdx.x == 0 && threadIdx.x < 64) {
        const size_t kb = (size_t)bh * NCHUNK * 64 + threadIdx.x;
        float a = 0.0f;
        #pragma unroll
        for (int c = 0; c < NCHUNK; c++) {
            const float t = Ksum[kb + c * 64];
            Ksum[kb + c * 64] = a;
            a += t;
        }
    }
}

// phase 2: out = (Q@M_prev + causal(QK^T)@V) / (Q@ksum_prev + rowsum(S) + 1e-6)
__global__ void __launch_bounds__(256)
attn_phase2(const ushort_t* __restrict__ qkv, const float* __restrict__ P,
            const float* __restrict__ Ksum, ushort_t* __restrict__ Out)
{
    const int c = blockIdx.x, h = blockIdx.y, b = blockIdx.z;
    const int tid = threadIdx.x;
    __shared__ ushort_t Qs[64][68], KsB[64][68], VsB[64][68];
    __shared__ float S[64][68];
    __shared__ float Mp[64][64];
    __shared__ float kp[64];
    __shared__ float partial[4][64];
    const size_t rowbase = (size_t)b * SEQ + c * 64;
    const size_t pbase = (((size_t)b * NH + h) * NCHUNK + c) * 4096;
    #pragma unroll
    for (int i = 0; i < 4; i++) {
        const int lin = tid + 256 * i;          // (t, d4) over 64x16
        const int t = lin >> 4, d4 = (lin & 15) * 4;
        const size_t gidx = (rowbase + t) * QSTR + h * HD + d4;
        *(uint2*)&Qs[t][d4]  = *(const uint2*)(qkv + gidx);
        *(uint2*)&KsB[t][d4] = *(const uint2*)(qkv + 1024 + gidx);
        *(uint2*)&VsB[t][d4] = *(const uint2*)(qkv + 2048 + gidx);
        *(float4*)&Mp[t][d4] = *(const float4*)(P + pbase + lin * 4);
    }
    if (tid < 64) kp[tid] = Ksum[(((size_t)b * NH + h) * NCHUNK + c) * 64 + tid];
    __syncthreads();

    const int t0 = (tid >> 4) * 4;
    const int c0 = (tid & 15) * 4;              // ii-block for S phase, e-block later

    // S = causal(Q K^T); masked entries written as 0
    {
        float accS[4][4] = {};
        for (int d4 = 0; d4 < 64; d4 += 4) {
            float qf[4][4], kf[4][4];
            #pragma unroll
            for (int i = 0; i < 4; i++) {
                unpack4(*(const uint2*)&Qs[t0 + i][d4], qf[i]);
                unpack4(*(const uint2*)&KsB[c0 + i][d4], kf[i]);
            }
            #pragma unroll
            for (int i = 0; i < 4; i++)
                #pragma unroll
                for (int j = 0; j < 4; j++)
                    #pragma unroll
                    for (int dd = 0; dd < 4; dd++)
                        accS[i][j] += qf[i][dd] * kf[j][dd];
        }
        #pragma unroll
        for (int i = 0; i < 4; i++) {
            float4 sv;
            sv.x = (c0 + 0 <= t0 + i) ? accS[i][0] : 0.0f;
            sv.y = (c0 + 1 <= t0 + i) ? accS[i][1] : 0.0f;
            sv.z = (c0 + 2 <= t0 + i) ? accS[i][2] : 0.0f;
            sv.w = (c0 + 3 <= t0 + i) ? accS[i][3] : 0.0f;
            *(float4*)&S[t0 + i][c0] = sv;
        }
    }
    __syncthreads();

    // den partials: quarter-range per thread
    {
        const int t = tid & 63, q = tid >> 6;
        const int base = q * 16;
        float a = 0.0f;
        #pragma unroll
        for (int ii = 0; ii < 16; ii++) a += S[t][base + ii];
        #pragma unroll
        for (int d = 0; d < 16; d++) a += b2f(Qs[t][base + d]) * kp[base + d];
        partial[q][t] = a;
    }
    __syncthreads();

    // out = S@V + Q@Mp, then /den
    float acc[4][4] = {};
    for (int ii = 0; ii < 64; ii++) {
        float vf[4];
        unpack4(*(const uint2*)&VsB[ii][c0], vf);
        #pragma unroll
        for (int i = 0; i < 4; i++) {
            const float s = S[t0 + i][ii];
            #pragma unroll
            for (int j = 0; j < 4; j++) acc[i][j] += s * vf[j];
        }
    }
    for (int d = 0; d < 64; d++) {
        const float4 mp = *(const float4*)&Mp[d][c0];
        #pragma unroll
        for (int i = 0; i < 4; i++) {
            const float qv = b2f(Qs[t0 + i][d]);
            acc[i][0] += qv * mp.x; acc[i][1] += qv * mp.y;
            acc[i][2] += qv * mp.z; acc[i][3] += qv * mp.w;
        }
    }
    #pragma unroll
    for (int i = 0; i < 4; i++) {
        const float dent = partial[0][t0 + i] + partial[1][t0 + i] +
                           partial[2][t0 + i] + partial[3][t0 + i] + 1e-6f;
        const float r = 1.0f / dent;
        ushort_t o[4];
        #pragma unroll
        for (int j = 0; j < 4; j++) o[j] = f2b(acc[i][j] * r);
        uint2 u2;
        u2.x = (unsigned int)o[0] | ((unsigned int)o[1] << 16);
        u2.y = (unsigned int)o[2] | ((unsigned int)o[3] << 16);
        *(uint2*)(Out + (rowbase + t0 + i) * DIM + h * HD + c0) = u2;
    }
}

// ---------------------------------------------------------------- launcher
extern "C" void kernel_launch(void* const* d_in, const int* in_sizes, int n_in,
                              void* d_out, int out_size, void* d_ws, size_t ws_size,
                              hipStream_t stream)
{
    const float* x      = (const float*)d_in[0];
    const float* Wq     = (const float*)d_in[1];
    const float* Wk     = (const float*)d_in[2];
    const float* Wv     = (const float*)d_in[3];
    const float* Wo     = (const float*)d_in[4];
    const float* ln1g   = (const float*)d_in[5];
    const float* ln1b   = (const float*)d_in[6];
    const float* ln2g   = (const float*)d_in[7];
    const float* ln2b   = (const float*)d_in[8];
    const float* cw1    = (const float*)d_in[9];
    const float* cb1    = (const float*)d_in[10];
    const float* cw2    = (const float*)d_in[11];
    const float* cb2    = (const float*)d_in[12];

    char* ws = (char*)d_ws;
    ushort_t* h     = (ushort_t*)(ws + OFF_H);
    ushort_t* qkv   = (ushort_t*)(ws + OFF_Q);
    float*    Pb    = (float*)(ws + OFF_P);
    float*    ksb   = (float*)(ws + OFF_KS);
    float*    x1    = (float*)(ws + OFF_X1);
    ushort_t* wqkvt = (ushort_t*)(ws + OFF_WQT);
    ushort_t* wot   = (ushort_t*)(ws + OFF_WOT);
    ushort_t* w1t   = (ushort_t*)(ws + OFF_W1T);
    ushort_t* w2t   = (ushort_t*)(ws + OFF_W2T);
    ushort_t* hid   = (ushort_t*)(ws + OFF_HIDB);
    float*    outp  = (float*)d_out;

    const dim3 tb(32, 8);
    // fused qkv weight^T: [3072][1024]
    transpose_f32_bf16<<<dim3(32, 32), tb, 0, stream>>>(Wq, wqkvt,                   DIM, DIM);
    transpose_f32_bf16<<<dim3(32, 32), tb, 0, stream>>>(Wk, wqkvt + 1024 * 1024,     DIM, DIM);
    transpose_f32_bf16<<<dim3(32, 32), tb, 0, stream>>>(Wv, wqkvt + 2 * 1024 * 1024, DIM, DIM);
    transpose_f32_bf16<<<dim3(32, 32), tb, 0, stream>>>(Wo, wot, DIM, DIM);
    for (int l = 0; l < 3; l++) {
        transpose_f32_bf16<<<dim3(128, 32), tb, 0, stream>>>(cw1 + (size_t)l * DIM * HID,
                                                             w1t + (size_t)l * HID * DIM, DIM, HID);
        transpose_f32_bf16<<<dim3(32, 128), tb, 0, stream>>>(cw2 + (size_t)l * HID * DIM,
                                                             w2t + (size_t)l * DIM * HID, HID, DIM);
    }

    ln_fwd<<<MROWS, 256, 0, stream>>>(x, ln1g, ln1b, h);

    // fused Q|K|V projection: [8192][3072], elu+1 on first 2048 cols
    // BN=128 -> 32x24 = 768 wg = 3 full waves of 256 CUs
    gemm256<128, ACT_QKV, false, false, false><<<dim3(32, 24), 512, 0, stream>>>(
        h, wqkvt, nullptr, nullptr, qkv, MROWS, QSTR, DIM);

    attn_phase1<<<dim3(NCHUNK, NH, NB), 256, 0, stream>>>(qkv, Pb, ksb);
    attn_prefix<<<dim3(16, 64), 256, 0, stream>>>(Pb, ksb);
    attn_phase2<<<dim3(NCHUNK, NH, NB), 256, 0, stream>>>(qkv, Pb, ksb, h);  // h := attn out

    // Wo: N=1024, BN=128 -> 32x8 = 256 wg (exact fill)
    gemm256<128, ACT_NONE, false, true, true><<<dim3(32, 8), 512, 0, stream>>>(
        h, wot, nullptr, x, x1, MROWS, DIM, DIM);

    ln_fwd<<<MROWS, 256, 0, stream>>>(x1, ln2g, ln2b, h);

    const ushort_t* cur = h;
    for (int l = 0; l < 3; l++) {
        // w1: N=4096, BN=256 -> 32x16 = 512 wg = 2 full waves
        gemm256<256, ACT_GELU, true, false, false><<<dim3(32, 16), 512, 0, stream>>>(
            cur, w1t + (size_t)l * HID * DIM, cb1 + (size_t)l * HID, nullptr, hid, MROWS, HID, DIM);
        if (l < 2) {
            // w2: N=1024 K=4096, BN=128 -> 256 wg (exact fill)
            gemm256<128, ACT_NONE, true, false, false><<<dim3(32, 8), 512, 0, stream>>>(
                hid, w2t + (size_t)l * DIM * HID, cb2 + (size_t)l * DIM, nullptr, h, MROWS, DIM, HID);
            cur = h;
        } else {
            gemm256<128, ACT_NONE, true, true, true><<<dim3(32, 8), 512, 0, stream>>>(
                hid, w2t + (size_t)l * DIM * HID, cb2 + (size_t)l * DIM, x1, outp, MROWS, DIM, HID);
        }
    }
    (void)in_sizes; (void)n_in; (void)out_size; (void)ws_size;
}